// Round 1
// baseline (250.299 us; speedup 1.0000x reference)
//
#include <hip/hip_runtime.h>

#define NUM_JOINTS 24

__device__ __constant__ int d_parents[NUM_JOINTS] = {
    -1, 0, 0, 0, 1, 2, 3, 4, 5, 6, 7, 8, 9, 9, 9, 12, 13, 14, 16, 17, 18, 19, 20, 21
};

// Kernel A: per-batch Rodrigues + kinematic chain compose.
// grid = (B), block = (64). Writes G as float[B][24][9] (row-major 3x3) into ws.
__global__ __launch_bounds__(64) void chain_kernel(const float* __restrict__ pose,
                                                   float* __restrict__ R) {
    __shared__ float L[NUM_JOINTS][9];
    __shared__ float G[NUM_JOINTS][9];
    const int b = blockIdx.x;
    const int tid = threadIdx.x;

    if (tid < NUM_JOINTS) {
        float x = pose[b * 72 + tid * 3 + 0];
        float y = pose[b * 72 + tid * 3 + 1];
        float z = pose[b * 72 + tid * 3 + 2];
        // reference: angle = norm(axisang + 1e-8); axis = axisang / angle
        float ax = x + 1e-8f, ay = y + 1e-8f, az = z + 1e-8f;
        float angle = sqrtf(ax * ax + ay * ay + az * az);
        float inv = 1.0f / angle;
        float ux = x * inv, uy = y * inv, uz = z * inv;
        float c = cosf(angle), s = sinf(angle), t = 1.0f - c;
        L[tid][0] = c + t * ux * ux;
        L[tid][1] = t * ux * uy - s * uz;
        L[tid][2] = t * ux * uz + s * uy;
        L[tid][3] = t * uy * ux + s * uz;
        L[tid][4] = c + t * uy * uy;
        L[tid][5] = t * uy * uz - s * ux;
        L[tid][6] = t * uz * ux - s * uy;
        L[tid][7] = t * uz * uy + s * ux;
        L[tid][8] = c + t * uz * uz;
    }
    __syncthreads();

    if (tid == 0) {
        // G[0] = L[0]; G[i] = G[parent[i]] @ L[i]
        #pragma unroll
        for (int e = 0; e < 9; e++) G[0][e] = L[0][e];
        for (int i = 1; i < NUM_JOINTS; i++) {
            int p = d_parents[i];
            #pragma unroll
            for (int r = 0; r < 3; r++) {
                #pragma unroll
                for (int cc = 0; cc < 3; cc++) {
                    G[i][r * 3 + cc] = G[p][r * 3 + 0] * L[i][0 * 3 + cc]
                                     + G[p][r * 3 + 1] * L[i][1 * 3 + cc]
                                     + G[p][r * 3 + 2] * L[i][2 * 3 + cc];
                }
            }
        }
    }
    __syncthreads();

    // coalesced write-out of 216 floats
    for (int idx = tid; idx < NUM_JOINTS * 9; idx += blockDim.x) {
        R[b * NUM_JOINTS * 9 + idx] = G[idx / 9][idx % 9];
    }
}

// Kernel B: per-vertex skinning. One thread handles 4 consecutive vertices
// (float4 loads/stores, 16 B/lane). M = sum_k w_k * G_k accumulated in regs;
// G values are wave-uniform -> scalar loads feeding SGPR operands of v_fma.
__global__ __launch_bounds__(256) void skin_kernel(const float* __restrict__ normals,
                                                   const float* __restrict__ weights,
                                                   const float* __restrict__ R,
                                                   float* __restrict__ out,
                                                   int N) {
    const int b = blockIdx.y;
    const int q = blockIdx.x * blockDim.x + threadIdx.x;  // quad index
    const int nq = N >> 2;                                // full quads
    const int rem = N & 3;

    const float* __restrict__ Rb = R + b * NUM_JOINTS * 9;

    if (q < nq) {
        const float4* __restrict__ Wb = (const float4*)(weights + (size_t)b * NUM_JOINTS * N);
        const float4* __restrict__ Nb = (const float4*)(normals + (size_t)b * 3 * N);
        float4* __restrict__ Ob = (float4*)(out + (size_t)b * 3 * N);

        float4 m[9];
        #pragma unroll
        for (int e = 0; e < 9; e++) m[e] = make_float4(0.f, 0.f, 0.f, 0.f);

        #pragma unroll
        for (int k = 0; k < NUM_JOINTS; k++) {
            float4 w = Wb[(size_t)k * nq + q];
            #pragma unroll
            for (int e = 0; e < 9; e++) {
                float r = Rb[k * 9 + e];  // wave-uniform
                m[e].x = fmaf(w.x, r, m[e].x);
                m[e].y = fmaf(w.y, r, m[e].y);
                m[e].z = fmaf(w.z, r, m[e].z);
                m[e].w = fmaf(w.w, r, m[e].w);
            }
        }

        float4 nx = Nb[(size_t)0 * nq + q];
        float4 ny = Nb[(size_t)1 * nq + q];
        float4 nz = Nb[(size_t)2 * nq + q];

        float4 o;
        // row 0
        o.x = fmaf(m[0].x, nx.x, fmaf(m[1].x, ny.x, m[2].x * nz.x));
        o.y = fmaf(m[0].y, nx.y, fmaf(m[1].y, ny.y, m[2].y * nz.y));
        o.z = fmaf(m[0].z, nx.z, fmaf(m[1].z, ny.z, m[2].z * nz.z));
        o.w = fmaf(m[0].w, nx.w, fmaf(m[1].w, ny.w, m[2].w * nz.w));
        Ob[(size_t)0 * nq + q] = o;
        // row 1
        o.x = fmaf(m[3].x, nx.x, fmaf(m[4].x, ny.x, m[5].x * nz.x));
        o.y = fmaf(m[3].y, nx.y, fmaf(m[4].y, ny.y, m[5].y * nz.y));
        o.z = fmaf(m[3].z, nx.z, fmaf(m[4].z, ny.z, m[5].z * nz.z));
        o.w = fmaf(m[3].w, nx.w, fmaf(m[4].w, ny.w, m[5].w * nz.w));
        Ob[(size_t)1 * nq + q] = o;
        // row 2
        o.x = fmaf(m[6].x, nx.x, fmaf(m[7].x, ny.x, m[8].x * nz.x));
        o.y = fmaf(m[6].y, nx.y, fmaf(m[7].y, ny.y, m[8].y * nz.y));
        o.z = fmaf(m[6].z, nx.z, fmaf(m[7].z, ny.z, m[8].z * nz.z));
        o.w = fmaf(m[6].w, nx.w, fmaf(m[7].w, ny.w, m[8].w * nz.w));
        Ob[(size_t)2 * nq + q] = o;
    } else if (rem != 0 && q == nq) {
        // scalar tail (not hit for N=100000, kept for generality)
        for (int t = 0; t < rem; t++) {
            int n = nq * 4 + t;
            float m[9];
            #pragma unroll
            for (int e = 0; e < 9; e++) m[e] = 0.f;
            for (int k = 0; k < NUM_JOINTS; k++) {
                float w = weights[(size_t)b * NUM_JOINTS * N + (size_t)k * N + n];
                #pragma unroll
                for (int e = 0; e < 9; e++) m[e] = fmaf(w, Rb[k * 9 + e], m[e]);
            }
            float vx = normals[(size_t)b * 3 * N + 0 * N + n];
            float vy = normals[(size_t)b * 3 * N + 1 * N + n];
            float vz = normals[(size_t)b * 3 * N + 2 * N + n];
            for (int i = 0; i < 3; i++) {
                out[(size_t)b * 3 * N + (size_t)i * N + n] =
                    fmaf(m[3 * i], vx, fmaf(m[3 * i + 1], vy, m[3 * i + 2] * vz));
            }
        }
    }
}

extern "C" void kernel_launch(void* const* d_in, const int* in_sizes, int n_in,
                              void* d_out, int out_size, void* d_ws, size_t ws_size,
                              hipStream_t stream) {
    const float* normals = (const float*)d_in[0];           // (B,3,N)
    const float* pose = (const float*)d_in[1];              // (B,72)
    const float* weights = (const float*)d_in[2];           // (B,24,N)
    float* out = (float*)d_out;                              // (B,3,N)
    float* R = (float*)d_ws;                                 // (B,24,9) scratch

    const int B = in_sizes[1] / 72;
    const int N = in_sizes[0] / (3 * B);

    chain_kernel<<<dim3(B), dim3(64), 0, stream>>>(pose, R);

    const int nq = (N + 3) >> 2;  // quads incl. partial tail handler
    const int gx = (nq + 255) / 256;
    skin_kernel<<<dim3(gx, B), dim3(256), 0, stream>>>(normals, weights, R, out, N);
}

// Round 2
// 249.627 us; speedup vs baseline: 1.0027x; 1.0027x over previous
//
#include <hip/hip_runtime.h>

#define NUM_JOINTS 24

__device__ __constant__ int d_parents[NUM_JOINTS] = {
    -1, 0, 0, 0, 1, 2, 3, 4, 5, 6, 7, 8, 9, 9, 9, 12, 13, 14, 16, 17, 18, 19, 20, 21
};

// Kernel A: per-batch Rodrigues + kinematic chain compose.
// grid = (B), block = (64). Writes G as float[B][24][9] (row-major 3x3) into ws.
__global__ __launch_bounds__(64) void chain_kernel(const float* __restrict__ pose,
                                                   float* __restrict__ R) {
    __shared__ float L[NUM_JOINTS][9];
    __shared__ float G[NUM_JOINTS][9];
    const int b = blockIdx.x;
    const int tid = threadIdx.x;

    if (tid < NUM_JOINTS) {
        float x = pose[b * 72 + tid * 3 + 0];
        float y = pose[b * 72 + tid * 3 + 1];
        float z = pose[b * 72 + tid * 3 + 2];
        // reference: angle = norm(axisang + 1e-8); axis = axisang / angle
        float ax = x + 1e-8f, ay = y + 1e-8f, az = z + 1e-8f;
        float angle = sqrtf(ax * ax + ay * ay + az * az);
        float inv = 1.0f / angle;
        float ux = x * inv, uy = y * inv, uz = z * inv;
        float c = cosf(angle), s = sinf(angle), t = 1.0f - c;
        L[tid][0] = c + t * ux * ux;
        L[tid][1] = t * ux * uy - s * uz;
        L[tid][2] = t * ux * uz + s * uy;
        L[tid][3] = t * uy * ux + s * uz;
        L[tid][4] = c + t * uy * uy;
        L[tid][5] = t * uy * uz - s * ux;
        L[tid][6] = t * uz * ux - s * uy;
        L[tid][7] = t * uz * uy + s * ux;
        L[tid][8] = c + t * uz * uz;
    }
    __syncthreads();

    if (tid == 0) {
        #pragma unroll
        for (int e = 0; e < 9; e++) G[0][e] = L[0][e];
        for (int i = 1; i < NUM_JOINTS; i++) {
            int p = d_parents[i];
            #pragma unroll
            for (int r = 0; r < 3; r++) {
                #pragma unroll
                for (int cc = 0; cc < 3; cc++) {
                    G[i][r * 3 + cc] = G[p][r * 3 + 0] * L[i][0 * 3 + cc]
                                     + G[p][r * 3 + 1] * L[i][1 * 3 + cc]
                                     + G[p][r * 3 + 2] * L[i][2 * 3 + cc];
                }
            }
        }
    }
    __syncthreads();

    for (int idx = tid; idx < NUM_JOINTS * 9; idx += blockDim.x) {
        R[b * NUM_JOINTS * 9 + idx] = G[idx / 9][idx % 9];
    }
}

__device__ __forceinline__ float4 fma4(float4 a, float s, float4 c) {
    return make_float4(fmaf(a.x, s, c.x), fmaf(a.y, s, c.y),
                       fmaf(a.z, s, c.z), fmaf(a.w, s, c.w));
}

// Kernel B: per-vertex skinning, 8 vertices per thread (2x float4 per stream).
// R staged in LDS padded to [24][12] -> 3x ds_read_b128 per joint, all lanes
// same address = broadcast, zero bank conflicts. No uniform global loads in
// the hot loop (the R1 kernel's 216 per-thread global_load_dword problem).
__global__ __launch_bounds__(256) void skin_kernel(const float* __restrict__ normals,
                                                   const float* __restrict__ weights,
                                                   const float* __restrict__ R,
                                                   float* __restrict__ out,
                                                   int N) {
    __shared__ float4 Rl[NUM_JOINTS][3];  // rows padded 9->12 floats, 16B aligned

    const int b = blockIdx.y;
    const int tid = threadIdx.x;

    // cooperative stage of 216 floats into padded LDS
    {
        float* Rf = (float*)Rl;
        const float* Rg = R + b * NUM_JOINTS * 9;
        if (tid < NUM_JOINTS * 9) {
            Rf[(tid / 9) * 12 + (tid % 9)] = Rg[tid];
        }
    }
    __syncthreads();

    const int q8 = blockIdx.x * blockDim.x + tid;  // index of 8-vertex group
    const int n8 = N >> 3;                         // full groups of 8
    const int nf4 = N >> 2;                        // float4 stride per row

    const float4* __restrict__ Wb = (const float4*)(weights + (size_t)b * NUM_JOINTS * N);
    const float4* __restrict__ Nb = (const float4*)(normals + (size_t)b * 3 * N);
    float4* __restrict__ Ob = (float4*)(out + (size_t)b * 3 * N);

    if (q8 < n8) {
        float4 m0[9], m1[9];
        #pragma unroll
        for (int e = 0; e < 9; e++) {
            m0[e] = make_float4(0.f, 0.f, 0.f, 0.f);
            m1[e] = make_float4(0.f, 0.f, 0.f, 0.f);
        }

        #pragma unroll 4
        for (int k = 0; k < NUM_JOINTS; k++) {
            float4 w0 = Wb[(size_t)k * nf4 + (q8 << 1)];
            float4 w1 = Wb[(size_t)k * nf4 + (q8 << 1) + 1];
            float4 r0 = Rl[k][0];  // elems 0..3
            float4 r1 = Rl[k][1];  // elems 4..7
            float4 r2 = Rl[k][2];  // elem 8 (+pad)
            m0[0] = fma4(w0, r0.x, m0[0]); m1[0] = fma4(w1, r0.x, m1[0]);
            m0[1] = fma4(w0, r0.y, m0[1]); m1[1] = fma4(w1, r0.y, m1[1]);
            m0[2] = fma4(w0, r0.z, m0[2]); m1[2] = fma4(w1, r0.z, m1[2]);
            m0[3] = fma4(w0, r0.w, m0[3]); m1[3] = fma4(w1, r0.w, m1[3]);
            m0[4] = fma4(w0, r1.x, m0[4]); m1[4] = fma4(w1, r1.x, m1[4]);
            m0[5] = fma4(w0, r1.y, m0[5]); m1[5] = fma4(w1, r1.y, m1[5]);
            m0[6] = fma4(w0, r1.z, m0[6]); m1[6] = fma4(w1, r1.z, m1[6]);
            m0[7] = fma4(w0, r1.w, m0[7]); m1[7] = fma4(w1, r1.w, m1[7]);
            m0[8] = fma4(w0, r2.x, m0[8]); m1[8] = fma4(w1, r2.x, m1[8]);
        }

        float4 nx0 = Nb[(size_t)0 * nf4 + (q8 << 1)], nx1 = Nb[(size_t)0 * nf4 + (q8 << 1) + 1];
        float4 ny0 = Nb[(size_t)1 * nf4 + (q8 << 1)], ny1 = Nb[(size_t)1 * nf4 + (q8 << 1) + 1];
        float4 nz0 = Nb[(size_t)2 * nf4 + (q8 << 1)], nz1 = Nb[(size_t)2 * nf4 + (q8 << 1) + 1];

        #pragma unroll
        for (int i = 0; i < 3; i++) {
            float4 o0, o1;
            o0.x = fmaf(m0[3*i].x, nx0.x, fmaf(m0[3*i+1].x, ny0.x, m0[3*i+2].x * nz0.x));
            o0.y = fmaf(m0[3*i].y, nx0.y, fmaf(m0[3*i+1].y, ny0.y, m0[3*i+2].y * nz0.y));
            o0.z = fmaf(m0[3*i].z, nx0.z, fmaf(m0[3*i+1].z, ny0.z, m0[3*i+2].z * nz0.z));
            o0.w = fmaf(m0[3*i].w, nx0.w, fmaf(m0[3*i+1].w, ny0.w, m0[3*i+2].w * nz0.w));
            o1.x = fmaf(m1[3*i].x, nx1.x, fmaf(m1[3*i+1].x, ny1.x, m1[3*i+2].x * nz1.x));
            o1.y = fmaf(m1[3*i].y, nx1.y, fmaf(m1[3*i+1].y, ny1.y, m1[3*i+2].y * nz1.y));
            o1.z = fmaf(m1[3*i].z, nx1.z, fmaf(m1[3*i+1].z, ny1.z, m1[3*i+2].z * nz1.z));
            o1.w = fmaf(m1[3*i].w, nx1.w, fmaf(m1[3*i+1].w, ny1.w, m1[3*i+2].w * nz1.w));
            Ob[(size_t)i * nf4 + (q8 << 1)] = o0;
            Ob[(size_t)i * nf4 + (q8 << 1) + 1] = o1;
        }
    } else if (q8 == n8 && (N & 7) != 0) {
        // scalar tail (not hit for N=100000)
        const float* Rf = (const float*)Rl;
        for (int n = n8 * 8; n < N; n++) {
            float m[9];
            #pragma unroll
            for (int e = 0; e < 9; e++) m[e] = 0.f;
            for (int k = 0; k < NUM_JOINTS; k++) {
                float w = weights[(size_t)b * NUM_JOINTS * N + (size_t)k * N + n];
                #pragma unroll
                for (int e = 0; e < 9; e++) m[e] = fmaf(w, Rf[k * 12 + e], m[e]);
            }
            float vx = normals[(size_t)b * 3 * N + 0 * N + n];
            float vy = normals[(size_t)b * 3 * N + 1 * N + n];
            float vz = normals[(size_t)b * 3 * N + 2 * N + n];
            for (int i = 0; i < 3; i++) {
                out[(size_t)b * 3 * N + (size_t)i * N + n] =
                    fmaf(m[3 * i], vx, fmaf(m[3 * i + 1], vy, m[3 * i + 2] * vz));
            }
        }
    }
}

extern "C" void kernel_launch(void* const* d_in, const int* in_sizes, int n_in,
                              void* d_out, int out_size, void* d_ws, size_t ws_size,
                              hipStream_t stream) {
    const float* normals = (const float*)d_in[0];           // (B,3,N)
    const float* pose = (const float*)d_in[1];              // (B,72)
    const float* weights = (const float*)d_in[2];           // (B,24,N)
    float* out = (float*)d_out;                              // (B,3,N)
    float* R = (float*)d_ws;                                 // (B,24,9) scratch

    const int B = in_sizes[1] / 72;
    const int N = in_sizes[0] / (3 * B);

    chain_kernel<<<dim3(B), dim3(64), 0, stream>>>(pose, R);

    const int n8 = (N + 7) >> 3;  // 8-vertex groups incl. tail handler
    const int gx = (n8 + 255) / 256;
    skin_kernel<<<dim3(gx, B), dim3(256), 0, stream>>>(normals, weights, R, out, N);
}

// Round 4
// 231.303 us; speedup vs baseline: 1.0821x; 1.0792x over previous
//
#include <hip/hip_runtime.h>

#define NUM_JOINTS 24

typedef float fvec4 __attribute__((ext_vector_type(4)));

// Ancestor path (root -> joint) for each joint, padded with -1.
// G_k = L[path[0]] @ L[path[1]] @ ... @ L[path[depth-1]]
__device__ __constant__ int d_chain[NUM_JOINTS][9] = {
    {0,-1,-1,-1,-1,-1,-1,-1,-1},
    {0,1,-1,-1,-1,-1,-1,-1,-1},
    {0,2,-1,-1,-1,-1,-1,-1,-1},
    {0,3,-1,-1,-1,-1,-1,-1,-1},
    {0,1,4,-1,-1,-1,-1,-1,-1},
    {0,2,5,-1,-1,-1,-1,-1,-1},
    {0,3,6,-1,-1,-1,-1,-1,-1},
    {0,1,4,7,-1,-1,-1,-1,-1},
    {0,2,5,8,-1,-1,-1,-1,-1},
    {0,3,6,9,-1,-1,-1,-1,-1},
    {0,1,4,7,10,-1,-1,-1,-1},
    {0,2,5,8,11,-1,-1,-1,-1},
    {0,3,6,9,12,-1,-1,-1,-1},
    {0,3,6,9,13,-1,-1,-1,-1},
    {0,3,6,9,14,-1,-1,-1,-1},
    {0,3,6,9,12,15,-1,-1,-1},
    {0,3,6,9,13,16,-1,-1,-1},
    {0,3,6,9,14,17,-1,-1,-1},
    {0,3,6,9,13,16,18,-1,-1},
    {0,3,6,9,14,17,19,-1,-1},
    {0,3,6,9,13,16,18,20,-1},
    {0,3,6,9,14,17,19,21,-1},
    {0,3,6,9,13,16,18,20,22},
    {0,3,6,9,14,17,19,21,23},
};

__device__ __forceinline__ fvec4 fma4(fvec4 a, float s, fvec4 c) {
    fvec4 r;
    r.x = fmaf(a.x, s, c.x); r.y = fmaf(a.y, s, c.y);
    r.z = fmaf(a.z, s, c.z); r.w = fmaf(a.w, s, c.w);
    return r;
}

// Fused kernel: each block recomputes the per-batch kinematic chain (cheap),
// then skins its slice of vertices. No workspace, no second launch.
// 8 vertices per thread (2x fvec4 per stream); R in LDS padded [24][12]
// -> 3x ds_read_b128 broadcast per joint, zero bank conflicts.
// Non-temporal global access: 192 MB streamed >> 32 MB L2.
__global__ __launch_bounds__(256) void skin_fused_kernel(
    const float* __restrict__ normals,
    const float* __restrict__ pose,
    const float* __restrict__ weights,
    float* __restrict__ out,
    int N) {
    __shared__ float L[NUM_JOINTS][9];
    __shared__ fvec4 Rl[NUM_JOINTS][3];  // global rots, rows padded 9->12 floats

    const int b = blockIdx.y;
    const int tid = threadIdx.x;

    // --- chain computation (lanes 0..23 of wave 0) ---
    if (tid < NUM_JOINTS) {
        float x = pose[b * 72 + tid * 3 + 0];
        float y = pose[b * 72 + tid * 3 + 1];
        float z = pose[b * 72 + tid * 3 + 2];
        // reference: angle = norm(axisang + 1e-8); axis = axisang / angle
        float ax = x + 1e-8f, ay = y + 1e-8f, az = z + 1e-8f;
        float angle = sqrtf(ax * ax + ay * ay + az * az);
        float inv = 1.0f / angle;
        float ux = x * inv, uy = y * inv, uz = z * inv;
        float c = cosf(angle), s = sinf(angle), t = 1.0f - c;
        L[tid][0] = c + t * ux * ux;
        L[tid][1] = t * ux * uy - s * uz;
        L[tid][2] = t * ux * uz + s * uy;
        L[tid][3] = t * uy * ux + s * uz;
        L[tid][4] = c + t * uy * uy;
        L[tid][5] = t * uy * uz - s * ux;
        L[tid][6] = t * uz * ux - s * uy;
        L[tid][7] = t * uz * uy + s * ux;
        L[tid][8] = c + t * uz * uz;
    }
    __syncthreads();

    if (tid < NUM_JOINTS) {
        // each lane composes its own ancestor path: G = L[c0] @ L[c1] @ ...
        float G[9];
        int j0 = d_chain[tid][0];  // always 0
        #pragma unroll
        for (int e = 0; e < 9; e++) G[e] = L[j0][e];
        #pragma unroll
        for (int d = 1; d < 9; d++) {
            int j = d_chain[tid][d];
            if (j >= 0) {
                float T[9];
                #pragma unroll
                for (int r = 0; r < 3; r++) {
                    #pragma unroll
                    for (int cc = 0; cc < 3; cc++) {
                        T[r * 3 + cc] = G[r * 3 + 0] * L[j][0 * 3 + cc]
                                      + G[r * 3 + 1] * L[j][1 * 3 + cc]
                                      + G[r * 3 + 2] * L[j][2 * 3 + cc];
                    }
                }
                #pragma unroll
                for (int e = 0; e < 9; e++) G[e] = T[e];
            }
        }
        float* Rf = (float*)Rl;
        #pragma unroll
        for (int e = 0; e < 9; e++) Rf[tid * 12 + e] = G[e];
    }
    __syncthreads();

    // --- skinning ---
    const int q8 = blockIdx.x * blockDim.x + tid;  // index of 8-vertex group
    const int n8 = N >> 3;                         // full groups of 8
    const int nf4 = N >> 2;                        // fvec4 stride per row

    const fvec4* __restrict__ Wb = (const fvec4*)(weights + (size_t)b * NUM_JOINTS * N);
    const fvec4* __restrict__ Nb = (const fvec4*)(normals + (size_t)b * 3 * N);
    fvec4* __restrict__ Ob = (fvec4*)(out + (size_t)b * 3 * N);

    if (q8 < n8) {
        fvec4 m0[9], m1[9];
        #pragma unroll
        for (int e = 0; e < 9; e++) {
            m0[e] = (fvec4)(0.f);
            m1[e] = (fvec4)(0.f);
        }

        #pragma unroll 4
        for (int k = 0; k < NUM_JOINTS; k++) {
            fvec4 w0 = __builtin_nontemporal_load(&Wb[(size_t)k * nf4 + (q8 << 1)]);
            fvec4 w1 = __builtin_nontemporal_load(&Wb[(size_t)k * nf4 + (q8 << 1) + 1]);
            fvec4 r0 = Rl[k][0];  // elems 0..3
            fvec4 r1 = Rl[k][1];  // elems 4..7
            fvec4 r2 = Rl[k][2];  // elem 8 (+pad)
            m0[0] = fma4(w0, r0.x, m0[0]); m1[0] = fma4(w1, r0.x, m1[0]);
            m0[1] = fma4(w0, r0.y, m0[1]); m1[1] = fma4(w1, r0.y, m1[1]);
            m0[2] = fma4(w0, r0.z, m0[2]); m1[2] = fma4(w1, r0.z, m1[2]);
            m0[3] = fma4(w0, r0.w, m0[3]); m1[3] = fma4(w1, r0.w, m1[3]);
            m0[4] = fma4(w0, r1.x, m0[4]); m1[4] = fma4(w1, r1.x, m1[4]);
            m0[5] = fma4(w0, r1.y, m0[5]); m1[5] = fma4(w1, r1.y, m1[5]);
            m0[6] = fma4(w0, r1.z, m0[6]); m1[6] = fma4(w1, r1.z, m1[6]);
            m0[7] = fma4(w0, r1.w, m0[7]); m1[7] = fma4(w1, r1.w, m1[7]);
            m0[8] = fma4(w0, r2.x, m0[8]); m1[8] = fma4(w1, r2.x, m1[8]);
        }

        fvec4 nx0 = __builtin_nontemporal_load(&Nb[(size_t)0 * nf4 + (q8 << 1)]);
        fvec4 nx1 = __builtin_nontemporal_load(&Nb[(size_t)0 * nf4 + (q8 << 1) + 1]);
        fvec4 ny0 = __builtin_nontemporal_load(&Nb[(size_t)1 * nf4 + (q8 << 1)]);
        fvec4 ny1 = __builtin_nontemporal_load(&Nb[(size_t)1 * nf4 + (q8 << 1) + 1]);
        fvec4 nz0 = __builtin_nontemporal_load(&Nb[(size_t)2 * nf4 + (q8 << 1)]);
        fvec4 nz1 = __builtin_nontemporal_load(&Nb[(size_t)2 * nf4 + (q8 << 1) + 1]);

        #pragma unroll
        for (int i = 0; i < 3; i++) {
            fvec4 o0, o1;
            o0.x = fmaf(m0[3*i].x, nx0.x, fmaf(m0[3*i+1].x, ny0.x, m0[3*i+2].x * nz0.x));
            o0.y = fmaf(m0[3*i].y, nx0.y, fmaf(m0[3*i+1].y, ny0.y, m0[3*i+2].y * nz0.y));
            o0.z = fmaf(m0[3*i].z, nx0.z, fmaf(m0[3*i+1].z, ny0.z, m0[3*i+2].z * nz0.z));
            o0.w = fmaf(m0[3*i].w, nx0.w, fmaf(m0[3*i+1].w, ny0.w, m0[3*i+2].w * nz0.w));
            o1.x = fmaf(m1[3*i].x, nx1.x, fmaf(m1[3*i+1].x, ny1.x, m1[3*i+2].x * nz1.x));
            o1.y = fmaf(m1[3*i].y, nx1.y, fmaf(m1[3*i+1].y, ny1.y, m1[3*i+2].y * nz1.y));
            o1.z = fmaf(m1[3*i].z, nx1.z, fmaf(m1[3*i+1].z, ny1.z, m1[3*i+2].z * nz1.z));
            o1.w = fmaf(m1[3*i].w, nx1.w, fmaf(m1[3*i+1].w, ny1.w, m1[3*i+2].w * nz1.w));
            __builtin_nontemporal_store(o0, &Ob[(size_t)i * nf4 + (q8 << 1)]);
            __builtin_nontemporal_store(o1, &Ob[(size_t)i * nf4 + (q8 << 1) + 1]);
        }
    } else if (q8 == n8 && (N & 7) != 0) {
        // scalar tail (not hit for N=100000)
        const float* Rf = (const float*)Rl;
        for (int n = n8 * 8; n < N; n++) {
            float m[9];
            #pragma unroll
            for (int e = 0; e < 9; e++) m[e] = 0.f;
            for (int k = 0; k < NUM_JOINTS; k++) {
                float w = weights[(size_t)b * NUM_JOINTS * N + (size_t)k * N + n];
                #pragma unroll
                for (int e = 0; e < 9; e++) m[e] = fmaf(w, Rf[k * 12 + e], m[e]);
            }
            float vx = normals[(size_t)b * 3 * N + 0 * N + n];
            float vy = normals[(size_t)b * 3 * N + 1 * N + n];
            float vz = normals[(size_t)b * 3 * N + 2 * N + n];
            for (int i = 0; i < 3; i++) {
                out[(size_t)b * 3 * N + (size_t)i * N + n] =
                    fmaf(m[3 * i], vx, fmaf(m[3 * i + 1], vy, m[3 * i + 2] * vz));
            }
        }
    }
}

extern "C" void kernel_launch(void* const* d_in, const int* in_sizes, int n_in,
                              void* d_out, int out_size, void* d_ws, size_t ws_size,
                              hipStream_t stream) {
    const float* normals = (const float*)d_in[0];  // (B,3,N)
    const float* pose = (const float*)d_in[1];     // (B,72)
    const float* weights = (const float*)d_in[2];  // (B,24,N)
    float* out = (float*)d_out;                    // (B,3,N)

    const int B = in_sizes[1] / 72;
    const int N = in_sizes[0] / (3 * B);

    const int n8 = (N + 7) >> 3;  // 8-vertex groups incl. tail handler
    const int gx = (n8 + 255) / 256;
    skin_fused_kernel<<<dim3(gx, B), dim3(256), 0, stream>>>(normals, pose, weights, out, N);
}

// Round 5
// 225.000 us; speedup vs baseline: 1.1124x; 1.0280x over previous
//
#include <hip/hip_runtime.h>

#define NUM_JOINTS 24

typedef float fvec4 __attribute__((ext_vector_type(4)));

// Ancestor path (root -> joint) for each joint, padded with -1.
// G_k = L[path[0]] @ L[path[1]] @ ... @ L[path[depth-1]]
__device__ __constant__ int d_chain[NUM_JOINTS][9] = {
    {0,-1,-1,-1,-1,-1,-1,-1,-1},
    {0,1,-1,-1,-1,-1,-1,-1,-1},
    {0,2,-1,-1,-1,-1,-1,-1,-1},
    {0,3,-1,-1,-1,-1,-1,-1,-1},
    {0,1,4,-1,-1,-1,-1,-1,-1},
    {0,2,5,-1,-1,-1,-1,-1,-1},
    {0,3,6,-1,-1,-1,-1,-1,-1},
    {0,1,4,7,-1,-1,-1,-1,-1},
    {0,2,5,8,-1,-1,-1,-1,-1},
    {0,3,6,9,-1,-1,-1,-1,-1},
    {0,1,4,7,10,-1,-1,-1,-1},
    {0,2,5,8,11,-1,-1,-1,-1},
    {0,3,6,9,12,-1,-1,-1,-1},
    {0,3,6,9,13,-1,-1,-1,-1},
    {0,3,6,9,14,-1,-1,-1,-1},
    {0,3,6,9,12,15,-1,-1,-1},
    {0,3,6,9,13,16,-1,-1,-1},
    {0,3,6,9,14,17,-1,-1,-1},
    {0,3,6,9,13,16,18,-1,-1},
    {0,3,6,9,14,17,19,-1,-1},
    {0,3,6,9,13,16,18,20,-1},
    {0,3,6,9,14,17,19,21,-1},
    {0,3,6,9,13,16,18,20,22},
    {0,3,6,9,14,17,19,21,23},
};

__device__ __forceinline__ fvec4 fma4(fvec4 a, float s, fvec4 c) {
    fvec4 r;
    r.x = fmaf(a.x, s, c.x); r.y = fmaf(a.y, s, c.y);
    r.z = fmaf(a.z, s, c.z); r.w = fmaf(a.w, s, c.w);
    return r;
}

// Fused chain + skinning. 8 verts/thread as TWO BLOCKED float4 streams
// (stream A: float4 idx q8; stream B: float4 idx q8+n8) so every global
// load/store instruction is unit-stride across the wave's 64 lanes
// (64 x 16 B = one aligned 1 KB segment) — the R4 interleaved layout had
// 32 B lane stride, doubling transactions per instruction.
// R staged in LDS padded [24][12] -> ds_read_b128 broadcasts, 0 conflicts.
// Non-temporal global access: 192 MB streamed >> 32 MB L2.
__global__ __launch_bounds__(256) void skin_fused_kernel(
    const float* __restrict__ normals,
    const float* __restrict__ pose,
    const float* __restrict__ weights,
    float* __restrict__ out,
    int N) {
    __shared__ float L[NUM_JOINTS][9];
    __shared__ fvec4 Rl[NUM_JOINTS][3];  // global rots, rows padded 9->12 floats

    const int b = blockIdx.y;
    const int tid = threadIdx.x;

    // --- chain computation (lanes 0..23 of wave 0) ---
    if (tid < NUM_JOINTS) {
        float x = pose[b * 72 + tid * 3 + 0];
        float y = pose[b * 72 + tid * 3 + 1];
        float z = pose[b * 72 + tid * 3 + 2];
        // reference: angle = norm(axisang + 1e-8); axis = axisang / angle
        float ax = x + 1e-8f, ay = y + 1e-8f, az = z + 1e-8f;
        float angle = sqrtf(ax * ax + ay * ay + az * az);
        float inv = 1.0f / angle;
        float ux = x * inv, uy = y * inv, uz = z * inv;
        float c = cosf(angle), s = sinf(angle), t = 1.0f - c;
        L[tid][0] = c + t * ux * ux;
        L[tid][1] = t * ux * uy - s * uz;
        L[tid][2] = t * ux * uz + s * uy;
        L[tid][3] = t * uy * ux + s * uz;
        L[tid][4] = c + t * uy * uy;
        L[tid][5] = t * uy * uz - s * ux;
        L[tid][6] = t * uz * ux - s * uy;
        L[tid][7] = t * uz * uy + s * ux;
        L[tid][8] = c + t * uz * uz;
    }
    __syncthreads();

    if (tid < NUM_JOINTS) {
        // each lane composes its own ancestor path: G = L[c0] @ L[c1] @ ...
        float G[9];
        int j0 = d_chain[tid][0];  // always 0
        #pragma unroll
        for (int e = 0; e < 9; e++) G[e] = L[j0][e];
        #pragma unroll
        for (int d = 1; d < 9; d++) {
            int j = d_chain[tid][d];
            if (j >= 0) {
                float T[9];
                #pragma unroll
                for (int r = 0; r < 3; r++) {
                    #pragma unroll
                    for (int cc = 0; cc < 3; cc++) {
                        T[r * 3 + cc] = G[r * 3 + 0] * L[j][0 * 3 + cc]
                                      + G[r * 3 + 1] * L[j][1 * 3 + cc]
                                      + G[r * 3 + 2] * L[j][2 * 3 + cc];
                    }
                }
                #pragma unroll
                for (int e = 0; e < 9; e++) G[e] = T[e];
            }
        }
        float* Rf = (float*)Rl;
        #pragma unroll
        for (int e = 0; e < 9; e++) Rf[tid * 12 + e] = G[e];
    }
    __syncthreads();

    // --- skinning ---
    const int q8 = blockIdx.x * blockDim.x + tid;  // thread's stream-A float4 idx
    const int n8 = N >> 3;                         // float4s per half (groups of 8)
    const int nf4 = N >> 2;                        // float4 stride per row

    const fvec4* __restrict__ Wb = (const fvec4*)(weights + (size_t)b * NUM_JOINTS * N);
    const fvec4* __restrict__ Nb = (const fvec4*)(normals + (size_t)b * 3 * N);
    fvec4* __restrict__ Ob = (fvec4*)(out + (size_t)b * 3 * N);

    if (q8 < n8) {
        const int qa = q8;        // stream A float4 index
        const int qb = q8 + n8;   // stream B float4 index

        fvec4 m0[9], m1[9];
        #pragma unroll
        for (int e = 0; e < 9; e++) {
            m0[e] = (fvec4)(0.f);
            m1[e] = (fvec4)(0.f);
        }

        #pragma unroll 4
        for (int k = 0; k < NUM_JOINTS; k++) {
            fvec4 w0 = __builtin_nontemporal_load(&Wb[(size_t)k * nf4 + qa]);
            fvec4 w1 = __builtin_nontemporal_load(&Wb[(size_t)k * nf4 + qb]);
            fvec4 r0 = Rl[k][0];  // elems 0..3
            fvec4 r1 = Rl[k][1];  // elems 4..7
            fvec4 r2 = Rl[k][2];  // elem 8 (+pad)
            m0[0] = fma4(w0, r0.x, m0[0]); m1[0] = fma4(w1, r0.x, m1[0]);
            m0[1] = fma4(w0, r0.y, m0[1]); m1[1] = fma4(w1, r0.y, m1[1]);
            m0[2] = fma4(w0, r0.z, m0[2]); m1[2] = fma4(w1, r0.z, m1[2]);
            m0[3] = fma4(w0, r0.w, m0[3]); m1[3] = fma4(w1, r0.w, m1[3]);
            m0[4] = fma4(w0, r1.x, m0[4]); m1[4] = fma4(w1, r1.x, m1[4]);
            m0[5] = fma4(w0, r1.y, m0[5]); m1[5] = fma4(w1, r1.y, m1[5]);
            m0[6] = fma4(w0, r1.z, m0[6]); m1[6] = fma4(w1, r1.z, m1[6]);
            m0[7] = fma4(w0, r1.w, m0[7]); m1[7] = fma4(w1, r1.w, m1[7]);
            m0[8] = fma4(w0, r2.x, m0[8]); m1[8] = fma4(w1, r2.x, m1[8]);
        }

        fvec4 nx0 = __builtin_nontemporal_load(&Nb[(size_t)0 * nf4 + qa]);
        fvec4 nx1 = __builtin_nontemporal_load(&Nb[(size_t)0 * nf4 + qb]);
        fvec4 ny0 = __builtin_nontemporal_load(&Nb[(size_t)1 * nf4 + qa]);
        fvec4 ny1 = __builtin_nontemporal_load(&Nb[(size_t)1 * nf4 + qb]);
        fvec4 nz0 = __builtin_nontemporal_load(&Nb[(size_t)2 * nf4 + qa]);
        fvec4 nz1 = __builtin_nontemporal_load(&Nb[(size_t)2 * nf4 + qb]);

        #pragma unroll
        for (int i = 0; i < 3; i++) {
            fvec4 o0, o1;
            o0.x = fmaf(m0[3*i].x, nx0.x, fmaf(m0[3*i+1].x, ny0.x, m0[3*i+2].x * nz0.x));
            o0.y = fmaf(m0[3*i].y, nx0.y, fmaf(m0[3*i+1].y, ny0.y, m0[3*i+2].y * nz0.y));
            o0.z = fmaf(m0[3*i].z, nx0.z, fmaf(m0[3*i+1].z, ny0.z, m0[3*i+2].z * nz0.z));
            o0.w = fmaf(m0[3*i].w, nx0.w, fmaf(m0[3*i+1].w, ny0.w, m0[3*i+2].w * nz0.w));
            o1.x = fmaf(m1[3*i].x, nx1.x, fmaf(m1[3*i+1].x, ny1.x, m1[3*i+2].x * nz1.x));
            o1.y = fmaf(m1[3*i].y, nx1.y, fmaf(m1[3*i+1].y, ny1.y, m1[3*i+2].y * nz1.y));
            o1.z = fmaf(m1[3*i].z, nx1.z, fmaf(m1[3*i+1].z, ny1.z, m1[3*i+2].z * nz1.z));
            o1.w = fmaf(m1[3*i].w, nx1.w, fmaf(m1[3*i+1].w, ny1.w, m1[3*i+2].w * nz1.w));
            __builtin_nontemporal_store(o0, &Ob[(size_t)i * nf4 + qa]);
            __builtin_nontemporal_store(o1, &Ob[(size_t)i * nf4 + qb]);
        }
    } else if (q8 == n8 && (N & 7) != 0) {
        // scalar tail: vertices [8*n8, N) (not hit for N=100000)
        const float* Rf = (const float*)Rl;
        for (int n = n8 * 8; n < N; n++) {
            float m[9];
            #pragma unroll
            for (int e = 0; e < 9; e++) m[e] = 0.f;
            for (int k = 0; k < NUM_JOINTS; k++) {
                float w = weights[(size_t)b * NUM_JOINTS * N + (size_t)k * N + n];
                #pragma unroll
                for (int e = 0; e < 9; e++) m[e] = fmaf(w, Rf[k * 12 + e], m[e]);
            }
            float vx = normals[(size_t)b * 3 * N + 0 * N + n];
            float vy = normals[(size_t)b * 3 * N + 1 * N + n];
            float vz = normals[(size_t)b * 3 * N + 2 * N + n];
            for (int i = 0; i < 3; i++) {
                out[(size_t)b * 3 * N + (size_t)i * N + n] =
                    fmaf(m[3 * i], vx, fmaf(m[3 * i + 1], vy, m[3 * i + 2] * vz));
            }
        }
    }
}

extern "C" void kernel_launch(void* const* d_in, const int* in_sizes, int n_in,
                              void* d_out, int out_size, void* d_ws, size_t ws_size,
                              hipStream_t stream) {
    const float* normals = (const float*)d_in[0];  // (B,3,N)
    const float* pose = (const float*)d_in[1];     // (B,72)
    const float* weights = (const float*)d_in[2];  // (B,24,N)
    float* out = (float*)d_out;                    // (B,3,N)

    const int B = in_sizes[1] / 72;
    const int N = in_sizes[0] / (3 * B);

    const int n8 = (N + 7) >> 3;  // 8-vertex groups incl. tail handler
    const int gx = (n8 + 255) / 256;
    skin_fused_kernel<<<dim3(gx, B), dim3(256), 0, stream>>>(normals, pose, weights, out, N);
}